// Round 1
// baseline (71.366 us; speedup 1.0000x reference)
//
#include <hip/hip_runtime.h>
#include <math.h>

// Problem constants (match reference)
#define NPOINTS 32768
#define NCELLS  5717   // 16*16 scaling + (1+4+16+64+256+1024+4096) detail cells

// Flattened cell table entry: contribution(point) = (A + Bp*r2u) * 2^(k*r2u)
// where r2u = (x-cx)^2 + (y-cy)^2 (unscaled); sigma scaling folded into k/Bp.
//  - scaling cells: A = c, Bp = 0, k = -0.5*log2(e)/sigma2
//  - ricker cells:  A = 2c, Bp = -c/sigma2, k = -0.5*log2(e)/sigma2
// tabA = (cx, cy, k, A), tabB = Bp

__global__ void build_table(const float* __restrict__ scaling,
                            const float* __restrict__ d0, const float* __restrict__ d1,
                            const float* __restrict__ d2, const float* __restrict__ d3,
                            const float* __restrict__ d4, const float* __restrict__ d5,
                            const float* __restrict__ d6,
                            float4* __restrict__ tabA, float* __restrict__ tabB) {
  int t = blockIdx.x * blockDim.x + threadIdx.x;
  if (t >= NCELLS) return;
  const float LOG2E = 1.4426950408889634f;
  float cx, cy, k, A, Bp;
  if (t < 256) {
    // scaling grid: 16x16, sigma2 = (0.9*1.6)^2 = 2.0736 (no epsilon in ref)
    int i = t >> 4, j = t & 15;
    cx = -1.0f + (2.0f / 15.0f) * (float)i;
    cy = -1.0f + (2.0f / 15.0f) * (float)j;
    float c = scaling[t];
    k = -0.5f * LOG2E / 2.0736f;
    A = c;
    Bp = 0.0f;
  } else {
    // detail levels: level L has size 2^L, offset (4^L - 1)/3 within details
    int u = t - 256;
    int off = 0, sz = 1, L = 0;
    while (u >= off + sz * sz) { off += sz * sz; sz <<= 1; ++L; }
    int local = u - off;
    int i = local / sz, j = local - i * sz;
    const float* dp = d0;
    if (L == 1) dp = d1;
    else if (L == 2) dp = d2;
    else if (L == 3) dp = d3;
    else if (L == 4) dp = d4;
    else if (L == 5) dp = d5;
    else if (L == 6) dp = d6;
    float c = dp[local];
    float sigma = 0.9f / (float)sz;
    float sigma2 = sigma * sigma + 1e-8f;
    float inv = 1.0f / sigma2;
    // jnp.linspace(-1,1,1) == [-1.0]
    float den = (sz > 1) ? (float)(sz - 1) : 1.0f;
    cx = (sz == 1) ? -1.0f : (-1.0f + 2.0f * (float)i / den);
    cy = (sz == 1) ? -1.0f : (-1.0f + 2.0f * (float)j / den);
    k = -0.5f * LOG2E * inv;
    A = 2.0f * c;
    Bp = -c * inv;
  }
  tabA[t] = make_float4(cx, cy, k, A);
  tabB[t] = Bp;
}

// Main: lane = point; blockIdx.y = cell chunk. Cell loads are wave-uniform
// (L1 broadcast); inner body = 2 sub, 2 mul, 3 fma, 1 v_exp per cell.
__global__ __launch_bounds__(256) void wavelet_main(
    const float2* __restrict__ coords,
    const float4* __restrict__ tabA, const float* __restrict__ tabB,
    float* __restrict__ partial, int chunk_sz) {
  int p = blockIdx.x * blockDim.x + threadIdx.x;
  int chunk = blockIdx.y;
  float2 c2 = coords[p];
  float x = c2.x * 0.1f;  // / DOMAIN
  float y = c2.y * 0.1f;
  int s = chunk * chunk_sz;
  int e = s + chunk_sz;
  if (e > NCELLS) e = NCELLS;
  float acc0 = 0.0f, acc1 = 0.0f;
  int i = s;
  for (; i + 2 <= e; i += 2) {
    float4 a0 = tabA[i];
    float b0 = tabB[i];
    float4 a1 = tabA[i + 1];
    float b1 = tabB[i + 1];
    float dx0 = x - a0.x, dy0 = y - a0.y;
    float r0 = fmaf(dy0, dy0, dx0 * dx0);
    float e0 = __builtin_amdgcn_exp2f(a0.z * r0);
    acc0 = fmaf(fmaf(b0, r0, a0.w), e0, acc0);
    float dx1 = x - a1.x, dy1 = y - a1.y;
    float r1 = fmaf(dy1, dy1, dx1 * dx1);
    float e1 = __builtin_amdgcn_exp2f(a1.z * r1);
    acc1 = fmaf(fmaf(b1, r1, a1.w), e1, acc1);
  }
  if (i < e) {
    float4 a0 = tabA[i];
    float b0 = tabB[i];
    float dx0 = x - a0.x, dy0 = y - a0.y;
    float r0 = fmaf(dy0, dy0, dx0 * dx0);
    float e0 = __builtin_amdgcn_exp2f(a0.z * r0);
    acc0 = fmaf(fmaf(b0, r0, a0.w), e0, acc0);
  }
  partial[(size_t)chunk * NPOINTS + p] = acc0 + acc1;
}

// Reduce partials + numerically-stable softplus (ref values reach ~181,
// naive log(1+exp(x)) would overflow to inf).
__global__ __launch_bounds__(256) void finalize(
    const float* __restrict__ partial, float* __restrict__ out, int chunks) {
  int p = blockIdx.x * blockDim.x + threadIdx.x;
  float sum = 0.0f;
  for (int c = 0; c < chunks; ++c) sum += partial[(size_t)c * NPOINTS + p];
  out[p] = fmaxf(sum, 0.0f) + log1pf(__expf(-fabsf(sum)));
}

extern "C" void kernel_launch(void* const* d_in, const int* in_sizes, int n_in,
                              void* d_out, int out_size, void* d_ws, size_t ws_size,
                              hipStream_t stream) {
  const float* coords  = (const float*)d_in[0];
  const float* scaling = (const float*)d_in[1];
  const float* d0 = (const float*)d_in[2];
  const float* d1 = (const float*)d_in[3];
  const float* d2 = (const float*)d_in[4];
  const float* d3 = (const float*)d_in[5];
  const float* d4 = (const float*)d_in[6];
  const float* d5 = (const float*)d_in[7];
  const float* d6 = (const float*)d_in[8];

  char* ws = (char*)d_ws;
  float4* tabA = (float4*)ws;                       // 5717 * 16 B = 91,472 B
  float*  tabB = (float*)(ws + 91472);              // 5717 *  4 B = 22,868 B
  size_t off_partial = 131072;                      // 16B-aligned, past table
  float* partial = (float*)(ws + off_partial);

  // chunk count: 16 if workspace allows (2 MiB partials), degrade otherwise
  int chunks = 16;
  size_t avail = (ws_size > off_partial) ? (ws_size - off_partial) : 0;
  int maxc = (int)(avail / ((size_t)NPOINTS * 4));
  if (maxc < 1) maxc = 1;
  if (chunks > maxc) chunks = maxc;
  int chunk_sz = (NCELLS + chunks - 1) / chunks;

  build_table<<<(NCELLS + 255) / 256, 256, 0, stream>>>(
      scaling, d0, d1, d2, d3, d4, d5, d6, tabA, tabB);

  dim3 grid(NPOINTS / 256, chunks);
  wavelet_main<<<grid, 256, 0, stream>>>(
      (const float2*)coords, tabA, tabB, partial, chunk_sz);

  finalize<<<NPOINTS / 256, 256, 0, stream>>>(partial, (float*)d_out, chunks);
}

// Round 2
// 12.849 us; speedup vs baseline: 5.5543x; 5.5543x over previous
//
#include <hip/hip_runtime.h>
#include <math.h>

#define NPOINTS 32768
#define NTASKS  8      // 4 scaling chunks + 1 (levels 0-3) + 3 windowed levels

// contribution of a ricker cell: c * (2 - r2u/s2) * exp(-0.5*r2u/s2)
//   = c * (2 + BS*r2u) * 2^(K*r2u),  BS = -1/s2, K = -0.5*log2(e)/s2
// scaling cell: c * 2^(Ks*r2u),  s2 = (0.9*1.6)^2 (no epsilon in ref)

#define LOG2E 1.4426950408889634

// Full (unwindowed) ricker level of size SZ (1,2,4,8): coeff loads are
// wave-uniform -> s_load; centers computed from loop index (SALU).
template<int SZ>
__device__ __forceinline__ float ricker_full(float x, float y,
                                             const float* __restrict__ c) {
  const double s2d = (0.9 / SZ) * (0.9 / SZ) + 1e-8;
  const float K  = (float)(-0.5 * LOG2E / s2d);
  const float BS = (float)(-1.0 / s2d);
  const float sp = (SZ > 1) ? 2.0f / (float)(SZ - 1) : 0.0f;
  float acc = 0.0f;
  for (int i = 0; i < SZ; ++i) {
    float cx = (SZ == 1) ? -1.0f : fmaf((float)i, sp, -1.0f);
    float dx = x - cx;
    float dx2 = dx * dx;
#pragma unroll
    for (int j = 0; j < SZ; ++j) {
      float cy = (SZ == 1) ? -1.0f : fmaf((float)j, sp, -1.0f);
      float dy = y - cy;
      float r2 = fmaf(dy, dy, dx2);
      float t = fmaf(BS, r2, 2.0f);
      acc = fmaf(c[i * SZ + j] * t, __builtin_amdgcn_exp2f(K * r2), acc);
    }
  }
  return acc;
}

// Windowed ricker level (SZ = 16/32/64): only the 8x8 cell window around the
// point matters (excluded cells are >= ~5.6 sigma away -> term < 4e-6).
// Window [i0, i0+7] with i0 = floor((x+1)/sp - 3.5) covers >= 2.5*sp on each
// side. Coeffs are per-lane gathers (tables <= 16 KB, L1/L2-resident).
template<int SZ>
__device__ __forceinline__ float ricker_win(float x, float y,
                                            const float* __restrict__ c) {
  const double s2d = (0.9 / SZ) * (0.9 / SZ) + 1e-8;
  const float K  = (float)(-0.5 * LOG2E / s2d);
  const float BS = (float)(-1.0 / s2d);
  const float sp = 2.0f / (float)(SZ - 1);
  const float inv_sp = (float)(SZ - 1) * 0.5f;
  int i0 = (int)floorf(fmaf(x + 1.0f, inv_sp, -3.5f));
  int j0 = (int)floorf(fmaf(y + 1.0f, inv_sp, -3.5f));
  i0 = min(max(i0, 0), SZ - 8);
  j0 = min(max(j0, 0), SZ - 8);
  float cx0 = fmaf((float)i0, sp, -1.0f);
  float cy0 = fmaf((float)j0, sp, -1.0f);
  float acc = 0.0f;
  for (int i = 0; i < 8; ++i) {
    float dx = x - fmaf((float)i, sp, cx0);
    float dx2 = dx * dx;
    const float* row = c + (i0 + i) * SZ + j0;
#pragma unroll
    for (int j = 0; j < 8; ++j) {
      float dy = y - fmaf((float)j, sp, cy0);
      float r2 = fmaf(dy, dy, dx2);
      float t = fmaf(BS, r2, 2.0f);
      acc = fmaf(row[j] * t, __builtin_amdgcn_exp2f(K * r2), acc);
    }
  }
  return acc;
}

__global__ __launch_bounds__(256) void wavelet_main(
    const float2* __restrict__ coords,
    const float* __restrict__ scaling,
    const float* __restrict__ d0, const float* __restrict__ d1,
    const float* __restrict__ d2, const float* __restrict__ d3,
    const float* __restrict__ d4, const float* __restrict__ d5,
    const float* __restrict__ d6,
    float* __restrict__ partial) {
  int p = blockIdx.x * 256 + threadIdx.x;
  int task = blockIdx.y;
  float2 c2 = coords[p];
  float x = c2.x * 0.1f;   // / DOMAIN
  float y = c2.y * 0.1f;
  float acc = 0.0f;

  if (task < 4) {
    // scaling grid 16x16, sigma2 = (0.9*1.6)^2 = 2.0736 exactly (no eps)
    const float KS = (float)(-0.5 * LOG2E / 2.0736);
    const float SPS = 2.0f / 15.0f;
    int base = task * 64;
    for (int t = 0; t < 64; ++t) {
      int cell = base + t;
      int i = cell >> 4, j = cell & 15;
      float c = scaling[cell];                    // uniform -> s_load
      float dx = x - fmaf((float)i, SPS, -1.0f);
      float dy = y - fmaf((float)j, SPS, -1.0f);
      float r2 = fmaf(dy, dy, dx * dx);
      acc = fmaf(c, __builtin_amdgcn_exp2f(KS * r2), acc);
    }
  } else if (task == 4) {
    acc += ricker_full<1>(x, y, d0);
    acc += ricker_full<2>(x, y, d1);
    acc += ricker_full<4>(x, y, d2);
    acc += ricker_full<8>(x, y, d3);
  } else if (task == 5) {
    acc = ricker_win<16>(x, y, d4);
  } else if (task == 6) {
    acc = ricker_win<32>(x, y, d5);
  } else {
    acc = ricker_win<64>(x, y, d6);
  }
  partial[task * NPOINTS + p] = acc;
}

// Sum task partials + numerically-stable softplus (values reach ~181).
__global__ __launch_bounds__(256) void finalize(
    const float* __restrict__ partial, float* __restrict__ out) {
  int p = blockIdx.x * 256 + threadIdx.x;
  float s = 0.0f;
#pragma unroll
  for (int t = 0; t < NTASKS; ++t) s += partial[t * NPOINTS + p];
  out[p] = fmaxf(s, 0.0f) + log1pf(__expf(-fabsf(s)));
}

extern "C" void kernel_launch(void* const* d_in, const int* in_sizes, int n_in,
                              void* d_out, int out_size, void* d_ws, size_t ws_size,
                              hipStream_t stream) {
  const float2* coords = (const float2*)d_in[0];
  const float* scaling = (const float*)d_in[1];
  const float* d0 = (const float*)d_in[2];
  const float* d1 = (const float*)d_in[3];
  const float* d2 = (const float*)d_in[4];
  const float* d3 = (const float*)d_in[5];
  const float* d4 = (const float*)d_in[6];
  const float* d5 = (const float*)d_in[7];
  const float* d6 = (const float*)d_in[8];

  float* partial = (float*)d_ws;   // NTASKS * NPOINTS * 4 = 1 MiB

  dim3 grid(NPOINTS / 256, NTASKS);
  wavelet_main<<<grid, 256, 0, stream>>>(
      coords, scaling, d0, d1, d2, d3, d4, d5, d6, partial);

  finalize<<<NPOINTS / 256, 256, 0, stream>>>(partial, (float*)d_out);
}

// Round 3
// 10.770 us; speedup vs baseline: 6.6261x; 1.1930x over previous
//
#include <hip/hip_runtime.h>
#include <math.h>

#define NPOINTS 32768
#define LOG2E 1.4426950408889634

// contribution of a ricker cell: c * (2 - r2u/s2) * exp(-0.5*r2u/s2)
//   = c * (2 + BS*r2u) * 2^(K*r2u),  BS = -1/s2, K = -0.5*log2(e)/s2
// scaling cell: c * 2^(Ks*r2u),  s2 = (0.9*1.6)^2 (no epsilon in ref)

// Full (unwindowed) ricker level of size SZ (1,2,4,8): coeff loads are
// wave-uniform; centers computed from loop index.
template<int SZ>
__device__ __forceinline__ float ricker_full(float x, float y,
                                             const float* __restrict__ c) {
  const double s2d = (0.9 / SZ) * (0.9 / SZ) + 1e-8;
  const float K  = (float)(-0.5 * LOG2E / s2d);
  const float BS = (float)(-1.0 / s2d);
  const float sp = (SZ > 1) ? 2.0f / (float)(SZ - 1) : 0.0f;
  float acc = 0.0f;
  for (int i = 0; i < SZ; ++i) {
    float cx = (SZ == 1) ? -1.0f : fmaf((float)i, sp, -1.0f);
    float dx = x - cx;
    float dx2 = dx * dx;
#pragma unroll
    for (int j = 0; j < SZ; ++j) {
      float cy = (SZ == 1) ? -1.0f : fmaf((float)j, sp, -1.0f);
      float dy = y - cy;
      float r2 = fmaf(dy, dy, dx2);
      float t = fmaf(BS, r2, 2.0f);
      acc = fmaf(c[i * SZ + j] * t, __builtin_amdgcn_exp2f(K * r2), acc);
    }
  }
  return acc;
}

// Windowed ricker level (SZ = 16/32/64): only the 8x8 cell window around the
// point matters (excluded cells are >= ~5.6 sigma away -> term < 4e-6 vs
// threshold 3.62). Coeffs are per-lane gathers (tables <= 16 KB, L1-resident).
template<int SZ>
__device__ __forceinline__ float ricker_win(float x, float y,
                                            const float* __restrict__ c) {
  const double s2d = (0.9 / SZ) * (0.9 / SZ) + 1e-8;
  const float K  = (float)(-0.5 * LOG2E / s2d);
  const float BS = (float)(-1.0 / s2d);
  const float sp = 2.0f / (float)(SZ - 1);
  const float inv_sp = (float)(SZ - 1) * 0.5f;
  int i0 = (int)floorf(fmaf(x + 1.0f, inv_sp, -3.5f));
  int j0 = (int)floorf(fmaf(y + 1.0f, inv_sp, -3.5f));
  i0 = min(max(i0, 0), SZ - 8);
  j0 = min(max(j0, 0), SZ - 8);
  float cx0 = fmaf((float)i0, sp, -1.0f);
  float cy0 = fmaf((float)j0, sp, -1.0f);
  float acc = 0.0f;
  for (int i = 0; i < 8; ++i) {
    float dx = x - fmaf((float)i, sp, cx0);
    float dx2 = dx * dx;
    const float* row = c + (i0 + i) * SZ + j0;
#pragma unroll
    for (int j = 0; j < 8; ++j) {
      float dy = y - fmaf((float)j, sp, cy0);
      float r2 = fmaf(dy, dy, dx2);
      float t = fmaf(BS, r2, 2.0f);
      acc = fmaf(row[j] * t, __builtin_amdgcn_exp2f(K * r2), acc);
    }
  }
  return acc;
}

// Single fused kernel: block = 512 threads = 8 waves; wave = task slice,
// lane = point. Partials meet in LDS, lanes 0-63 reduce + softplus + store.
// Eliminates the finalize kernel and the 1 MiB partial round-trip.
__global__ __launch_bounds__(512) void wavelet_fused(
    const float2* __restrict__ coords,
    const float* __restrict__ scaling,
    const float* __restrict__ d0, const float* __restrict__ d1,
    const float* __restrict__ d2, const float* __restrict__ d3,
    const float* __restrict__ d4, const float* __restrict__ d5,
    const float* __restrict__ d6,
    float* __restrict__ out) {
  __shared__ float red[8][64];
  int lane = threadIdx.x & 63;
  int slice = __builtin_amdgcn_readfirstlane(threadIdx.x >> 6);
  int p = blockIdx.x * 64 + lane;
  float2 c2 = coords[p];
  float x = c2.x * 0.1f;   // / DOMAIN
  float y = c2.y * 0.1f;
  float acc = 0.0f;

  if (slice < 4) {
    // scaling grid 16x16, sigma2 = (0.9*1.6)^2 = 2.0736 exactly (no eps)
    const float KS = (float)(-0.5 * LOG2E / 2.0736);
    const float SPS = 2.0f / 15.0f;
    int base = slice * 64;
    for (int t = 0; t < 64; ++t) {
      int cell = base + t;
      int i = cell >> 4, j = cell & 15;
      float c = scaling[cell];                    // scalar (uniform) load
      float dx = x - fmaf((float)i, SPS, -1.0f);
      float dy = y - fmaf((float)j, SPS, -1.0f);
      float r2 = fmaf(dy, dy, dx * dx);
      acc = fmaf(c, __builtin_amdgcn_exp2f(KS * r2), acc);
    }
  } else if (slice == 4) {
    acc += ricker_full<1>(x, y, d0);
    acc += ricker_full<2>(x, y, d1);
    acc += ricker_full<4>(x, y, d2);
    acc += ricker_full<8>(x, y, d3);
  } else if (slice == 5) {
    acc = ricker_win<16>(x, y, d4);
  } else if (slice == 6) {
    acc = ricker_win<32>(x, y, d5);
  } else {
    acc = ricker_win<64>(x, y, d6);
  }

  red[slice][lane] = acc;
  __syncthreads();

  if (threadIdx.x < 64) {
    float s = 0.0f;
#pragma unroll
    for (int t = 0; t < 8; ++t) s += red[t][threadIdx.x];
    // numerically-stable softplus (values reach ~181)
    out[p] = fmaxf(s, 0.0f) + log1pf(__expf(-fabsf(s)));
  }
}

extern "C" void kernel_launch(void* const* d_in, const int* in_sizes, int n_in,
                              void* d_out, int out_size, void* d_ws, size_t ws_size,
                              hipStream_t stream) {
  const float2* coords = (const float2*)d_in[0];
  const float* scaling = (const float*)d_in[1];
  const float* d0 = (const float*)d_in[2];
  const float* d1 = (const float*)d_in[3];
  const float* d2 = (const float*)d_in[4];
  const float* d3 = (const float*)d_in[5];
  const float* d4 = (const float*)d_in[6];
  const float* d5 = (const float*)d_in[7];
  const float* d6 = (const float*)d_in[8];

  wavelet_fused<<<NPOINTS / 64, 512, 0, stream>>>(
      coords, scaling, d0, d1, d2, d3, d4, d5, d6, (float*)d_out);
}

// Round 4
// 9.670 us; speedup vs baseline: 7.3803x; 1.1138x over previous
//
#include <hip/hip_runtime.h>
#include <math.h>

#define NPOINTS 32768
#define LOG2E 1.4426950408889634

__device__ __forceinline__ float ex2(float v) { return __builtin_amdgcn_exp2f(v); }

// Ricker cell: c*(2 - r2/s2)*exp(-r2/(2 s2)) = c*((2+BS*dx2) + BS*dy2) * Ex[i]*Ey[j]
// with BS = -1/s2, Ex = 2^(K dx2), Ey = 2^(K dy2), K = -0.5*log2(e)/s2.
// Separability removes the per-cell transcendental: 4 VALU ops per cell.

// Scaling sum (16x16 Gaussian, s2 = (0.9*1.6)^2 exactly, no epsilon):
// sum_ij c[i][j] Ex[i] Ey[j]  — bilinear form, rows [R0,R1).
template<int R0, int R1>
__device__ __forceinline__ float scaling_sep(float x, float y,
                                             const float* __restrict__ c) {
  const float KS = (float)(-0.5 * LOG2E / 2.0736);
  const float SPS = 2.0f / 15.0f;
  float Ey[16];
#pragma unroll
  for (int j = 0; j < 16; ++j) {
    float dy = y - fmaf((float)j, SPS, -1.0f);
    Ey[j] = ex2(KS * (dy * dy));
  }
  float acc = 0.0f;
#pragma unroll
  for (int i = R0; i < R1; ++i) {
    float dx = x - fmaf((float)i, SPS, -1.0f);
    float Exi = ex2(KS * (dx * dx));
    float rd = 0.0f;
#pragma unroll
    for (int j = 0; j < 16; ++j) rd = fmaf(c[i * 16 + j], Ey[j], rd);  // s_loads
    acc = fmaf(Exi, rd, acc);
  }
  return acc;
}

// Level 0: single cell at (-1,-1).
__device__ __forceinline__ float ricker_l0(float x, float y,
                                           const float* __restrict__ c) {
  const double s2d = 0.81 + 1e-8;
  const float K = (float)(-0.5 * LOG2E / s2d);
  const float BS = (float)(-1.0 / s2d);
  float dx = x + 1.0f, dy = y + 1.0f;
  float r2 = fmaf(dy, dy, dx * dx);
  return c[0] * fmaf(BS, r2, 2.0f) * ex2(K * r2);
}

// Full separable ricker level, SZ in {2,4,8}, rows [R0,R1). Coeff loads uniform.
template<int SZ, int R0, int R1>
__device__ __forceinline__ float ricker_full_sep(float x, float y,
                                                 const float* __restrict__ c) {
  const double s2d = (0.9 / SZ) * (0.9 / SZ) + 1e-8;
  const float K = (float)(-0.5 * LOG2E / s2d);
  const float BS = (float)(-1.0 / s2d);
  const float sp = 2.0f / (float)(SZ - 1);
  float Ey[SZ], dy2[SZ];
#pragma unroll
  for (int j = 0; j < SZ; ++j) {
    float dy = y - fmaf((float)j, sp, -1.0f);
    dy2[j] = dy * dy;
    Ey[j] = ex2(K * dy2[j]);
  }
  float acc = 0.0f;
#pragma unroll
  for (int i = R0; i < R1; ++i) {
    float dx = x - fmaf((float)i, sp, -1.0f);
    float dx2 = dx * dx;
    float Exi = ex2(K * dx2);
    float Ai = fmaf(BS, dx2, 2.0f);
#pragma unroll
    for (int j = 0; j < SZ; ++j) {
      float t = fmaf(BS, dy2[j], Ai);
      acc = fmaf(c[i * SZ + j] * t, Exi * Ey[j], acc);
    }
  }
  return acc;
}

// Windowed separable ricker level (SZ = 16/32/64): 8-row x 12-col window,
// col start aligned to 4 -> three aligned float4 loads per row. Margin >= 3
// cells = 6.7 sigma on every side (excluded terms < 1e-9). Rows [R0,R1) of
// the window so one level can be split across waves.
template<int SZ, int R0, int R1>
__device__ __forceinline__ float ricker_win_sep(float x, float y,
                                                const float* __restrict__ c) {
  const double s2d = (0.9 / SZ) * (0.9 / SZ) + 1e-8;
  const float K = (float)(-0.5 * LOG2E / s2d);
  const float BS = (float)(-1.0 / s2d);
  const float sp = 2.0f / (float)(SZ - 1);
  const float inv_sp = (float)(SZ - 1) * 0.5f;
  int fi = (int)floorf((x + 1.0f) * inv_sp);
  int fj = (int)floorf((y + 1.0f) * inv_sp);
  int i0 = min(max(fi - 3, 0), SZ - 8);
  int j0 = min(max((fj - 4) & ~3, 0), SZ - 12);
  float cx0 = fmaf((float)i0, sp, -1.0f);
  float cy0 = fmaf((float)j0, sp, -1.0f);
  float Ey[12], dy2[12];
#pragma unroll
  for (int j = 0; j < 12; ++j) {
    float dy = y - fmaf((float)j, sp, cy0);
    dy2[j] = dy * dy;
    Ey[j] = ex2(K * dy2[j]);
  }
  float acc = 0.0f;
#pragma unroll
  for (int i = R0; i < R1; ++i) {
    float dx = x - fmaf((float)i, sp, cx0);
    float dx2 = dx * dx;
    float Exi = ex2(K * dx2);
    float Ai = fmaf(BS, dx2, 2.0f);
    const float4* rp = (const float4*)(c + (i0 + i) * SZ + j0);  // 16B aligned
    float4 ra = rp[0], rb = rp[1], rc = rp[2];
    float rv[12] = {ra.x, ra.y, ra.z, ra.w, rb.x, rb.y, rb.z, rb.w,
                    rc.x, rc.y, rc.z, rc.w};
#pragma unroll
    for (int j = 0; j < 12; ++j) {
      float t = fmaf(BS, dy2[j], Ai);
      acc = fmaf(rv[j] * t, Exi * Ey[j], acc);
    }
  }
  return acc;
}

// One fused kernel: block = 512 threads = 8 waves; wave = work slice,
// lane = point. Partials meet in LDS; wave 0 reduces + softplus + stores.
__global__ __launch_bounds__(512) void wavelet_fused(
    const float2* __restrict__ coords,
    const float* __restrict__ scaling,
    const float* __restrict__ d0, const float* __restrict__ d1,
    const float* __restrict__ d2, const float* __restrict__ d3,
    const float* __restrict__ d4, const float* __restrict__ d5,
    const float* __restrict__ d6,
    float* __restrict__ out) {
  __shared__ float red[8][64];
  int lane = threadIdx.x & 63;
  int slice = __builtin_amdgcn_readfirstlane(threadIdx.x >> 6);
  int p = blockIdx.x * 64 + lane;
  float2 c2 = coords[p];
  float x = c2.x * 0.1f;   // / DOMAIN
  float y = c2.y * 0.1f;
  float acc = 0.0f;

  switch (slice) {
    case 0: acc = scaling_sep<0, 8>(x, y, scaling); break;
    case 1: acc = scaling_sep<8, 16>(x, y, scaling); break;
    case 2: acc = ricker_l0(x, y, d0)
                + ricker_full_sep<2, 0, 2>(x, y, d1)
                + ricker_full_sep<4, 0, 4>(x, y, d2)
                + ricker_full_sep<8, 0, 4>(x, y, d3); break;
    case 3: acc = ricker_full_sep<8, 4, 8>(x, y, d3); break;
    case 4: acc = ricker_win_sep<16, 0, 8>(x, y, d4); break;
    case 5: acc = ricker_win_sep<32, 0, 8>(x, y, d5); break;
    case 6: acc = ricker_win_sep<64, 0, 4>(x, y, d6); break;
    default: acc = ricker_win_sep<64, 4, 8>(x, y, d6); break;
  }

  red[slice][lane] = acc;
  __syncthreads();

  if (threadIdx.x < 64) {
    float s = 0.0f;
#pragma unroll
    for (int t = 0; t < 8; ++t) s += red[t][threadIdx.x];
    // numerically-stable softplus (values reach ~181)
    out[p] = fmaxf(s, 0.0f) + log1pf(__expf(-fabsf(s)));
  }
}

extern "C" void kernel_launch(void* const* d_in, const int* in_sizes, int n_in,
                              void* d_out, int out_size, void* d_ws, size_t ws_size,
                              hipStream_t stream) {
  const float2* coords = (const float2*)d_in[0];
  const float* scaling = (const float*)d_in[1];
  const float* d0 = (const float*)d_in[2];
  const float* d1 = (const float*)d_in[3];
  const float* d2 = (const float*)d_in[4];
  const float* d3 = (const float*)d_in[5];
  const float* d4 = (const float*)d_in[6];
  const float* d5 = (const float*)d_in[7];
  const float* d6 = (const float*)d_in[8];

  wavelet_fused<<<NPOINTS / 64, 512, 0, stream>>>(
      coords, scaling, d0, d1, d2, d3, d4, d5, d6, (float*)d_out);
}